// Round 1
// baseline (92.120 us; speedup 1.0000x reference)
//
#include <hip/hip_runtime.h>

// Head: fused GEMM (M=204800, K=128, N=84->96 padded) + DFL softmax + box decode + sigmoid.
// f16 MFMA 16x16x32; x read fp32 from HBM once, converted in-register.

typedef _Float16 half8 __attribute__((ext_vector_type(8)));
typedef float f32x4v __attribute__((ext_vector_type(4)));

constexpr int Hh = 80, Ww = 80, Cc = 128;
constexpr int HW = Hh * Ww;          // 6400
constexpr int NPAD = 96;             // 6 tiles of 16 (64 box + 20 cls + 12 pad)
constexpr int WT_STRIDE = 136;       // f16 elems; 272 B row = 16B-aligned, low bank conflict

__global__ void head_kernel(const float* __restrict__ x,
                            const float* __restrict__ w_box,
                            const float* __restrict__ b_box,
                            const float* __restrict__ w_cls,
                            const float* __restrict__ b_cls,
                            const int*   __restrict__ stride_p,
                            float* __restrict__ out)
{
    __shared__ __align__(16) _Float16 Wt[NPAD][WT_STRIDE]; // Wt[ch][k]
    __shared__ float bias_s[NPAD];

    const int tid = threadIdx.x;

    // Stage weights transposed into LDS (coalesced global reads: consecutive tid -> consecutive ch)
    for (int idx = tid; idx < NPAD * Cc; idx += 256) {
        int k  = idx / NPAD;
        int ch = idx - k * NPAD;
        float wv = 0.f;
        if (ch < 64)      wv = w_box[k * 64 + ch];
        else if (ch < 84) wv = w_cls[k * 20 + (ch - 64)];
        Wt[ch][k] = (_Float16)wv;
    }
    if (tid < NPAD) {
        float bv = 0.f;
        if (tid < 64)      bv = b_box[tid];
        else if (tid < 84) bv = b_cls[tid - 64];
        bias_s[tid] = bv;
    }
    __syncthreads();

    const int wave = tid >> 6;
    const int lane = tid & 63;
    const int col  = lane & 15;     // A row-in-tile / B col / C col
    const int g    = lane >> 4;     // lane quarter-group

    const int mbase = blockIdx.x * 128 + wave * 32;   // 1600 blocks * 128 rows = 204800

    f32x4v acc[2][6];
    #pragma unroll
    for (int i = 0; i < 2; ++i)
        #pragma unroll
        for (int j = 0; j < 6; ++j)
            acc[i][j] = (f32x4v){0.f, 0.f, 0.f, 0.f};

    const float* xr0 = x + (size_t)(mbase + col) * Cc;        // row-tile 0
    const float* xr1 = x + (size_t)(mbase + 16 + col) * Cc;   // row-tile 1

    #pragma unroll
    for (int ks = 0; ks < 4; ++ks) {
        half8 bfrag[6];
        #pragma unroll
        for (int nt = 0; nt < 6; ++nt)
            bfrag[nt] = *(const half8*)&Wt[nt * 16 + col][ks * 32 + g * 8];

        #pragma unroll
        for (int rt = 0; rt < 2; ++rt) {
            const float* xp = (rt ? xr1 : xr0) + ks * 32 + g * 8;
            f32x4v lo = *(const f32x4v*)xp;
            f32x4v hi = *(const f32x4v*)(xp + 4);
            half8 a;
            a[0] = (_Float16)lo[0]; a[1] = (_Float16)lo[1];
            a[2] = (_Float16)lo[2]; a[3] = (_Float16)lo[3];
            a[4] = (_Float16)hi[0]; a[5] = (_Float16)hi[1];
            a[6] = (_Float16)hi[2]; a[7] = (_Float16)hi[3];
            #pragma unroll
            for (int nt = 0; nt < 6; ++nt)
                acc[rt][nt] = __builtin_amdgcn_mfma_f32_16x16x32_f16(a, bfrag[nt], acc[rt][nt], 0, 0, 0);
        }
    }

    const float sf = (float)stride_p[0];
    float bl[6];
    #pragma unroll
    for (int nt = 0; nt < 6; ++nt) bl[nt] = bias_s[nt * 16 + col];

    #pragma unroll
    for (int rt = 0; rt < 2; ++rt) {
        // DFL: softmax over 16 channels (spread across the 16 lanes of each quarter-group),
        // then expectation with bins = col index.
        float dfl[4][4];  // [t][reg]
        #pragma unroll
        for (int t = 0; t < 4; ++t) {
            #pragma unroll
            for (int r = 0; r < 4; ++r) {
                float v = acc[rt][t][r] + bl[t];
                float mx = v;
                #pragma unroll
                for (int off = 8; off >= 1; off >>= 1)
                    mx = fmaxf(mx, __shfl_xor(mx, off, 64));
                float e = __expf(v - mx);
                float s = e;
                float ws = e * (float)col;
                #pragma unroll
                for (int off = 8; off >= 1; off >>= 1) {
                    s  += __shfl_xor(s, off, 64);
                    ws += __shfl_xor(ws, off, 64);
                }
                dfl[t][r] = ws / s;
            }
        }
        #pragma unroll
        for (int r = 0; r < 4; ++r) {
            const int m  = mbase + rt * 16 + g * 4 + r;  // C row = 4*g + r
            const int pos = m % HW;
            const int yp  = pos / Ww;
            const int xp  = pos - yp * Ww;
            const float ax = ((float)xp + 0.5f) * sf;
            const float ay = ((float)yp + 0.5f) * sf;
            const float d0 = dfl[0][r], d1 = dfl[1][r], d2 = dfl[2][r], d3 = dfl[3][r];
            const float w2 = d2 - d0, w3 = d3 - d1;
            float* op = out + (size_t)m * 24;
            if (col < 4) {
                float bv = (col == 0) ? (ax + 0.5f * w2)
                         : (col == 1) ? (ay + 0.5f * w3)
                         : (col == 2) ? w2 : w3;
                op[col] = bv;
            }
            op[4 + col] = 1.f / (1.f + __expf(-(acc[rt][4][r] + bl[4])));
            if (col < 4)
                op[20 + col] = 1.f / (1.f + __expf(-(acc[rt][5][r] + bl[5])));
        }
    }
}

extern "C" void kernel_launch(void* const* d_in, const int* in_sizes, int n_in,
                              void* d_out, int out_size, void* d_ws, size_t ws_size,
                              hipStream_t stream) {
    const float* x     = (const float*)d_in[0];
    const float* w_box = (const float*)d_in[1];
    const float* b_box = (const float*)d_in[2];
    const float* w_cls = (const float*)d_in[3];
    const float* b_cls = (const float*)d_in[4];
    const int* stride_p = (const int*)d_in[5];
    float* out = (float*)d_out;

    dim3 grid(1600), block(256);
    hipLaunchKernelGGL(head_kernel, grid, block, 0, stream,
                       x, w_box, b_box, w_cls, b_cls, stride_p, out);
}

// Round 2
// 34.695 us; speedup vs baseline: 2.6552x; 2.6552x over previous
//
#include <hip/hip_runtime.h>

// Head: fused GEMM (M=204800, K=128, N=84->96 padded) + DFL softmax + box decode + sigmoid.
// Swapped-operand MFMA: D = Wt * x^T, so D-row = output channel (lane-local softmax),
// D-col = spatial row. f16 16x16x32 MFMA, fp32 accumulate.

typedef _Float16 half8 __attribute__((ext_vector_type(8)));
typedef float f32x4v __attribute__((ext_vector_type(4)));

constexpr int Ww = 80;
constexpr int HW = 6400;
constexpr int Cc = 128;
constexpr int NPAD = 96;             // 6 N-tiles of 16: 64 box + 20 cls + 12 pad
constexpr int WT_STRIDE = 136;       // f16 elems; 272B row → balanced 8-group b128 reads

__device__ __forceinline__ float sigm(float v) {
    return 1.f / (1.f + __expf(-v));
}

__global__ void head_kernel(const float* __restrict__ x,
                            const float* __restrict__ w_box,
                            const float* __restrict__ b_box,
                            const float* __restrict__ w_cls,
                            const float* __restrict__ b_cls,
                            const int*   __restrict__ stride_p,
                            float* __restrict__ out)
{
    __shared__ __align__(16) _Float16 Wt[NPAD][WT_STRIDE]; // Wt[ch][k]
    __shared__ __align__(16) float bias_s[NPAD];

    const int tid = threadIdx.x;

    // ---- stage Wt[ch][k] = w[k][ch] (f16), vectorized float4 along ch ----
    for (int i = tid; i < 128 * 16; i += 256) {          // box: 8 iters/thread
        int k  = i >> 4;
        int c4 = (i & 15) << 2;
        f32x4v v = *(const f32x4v*)&w_box[k * 64 + c4];
        Wt[c4 + 0][k] = (_Float16)v[0];
        Wt[c4 + 1][k] = (_Float16)v[1];
        Wt[c4 + 2][k] = (_Float16)v[2];
        Wt[c4 + 3][k] = (_Float16)v[3];
    }
    for (int i = tid; i < 128 * 5; i += 256) {           // cls: ~2.5 iters/thread
        int k  = i / 5;
        int c4 = (i - k * 5) << 2;
        f32x4v v = *(const f32x4v*)&w_cls[k * 20 + c4];
        Wt[64 + c4 + 0][k] = (_Float16)v[0];
        Wt[64 + c4 + 1][k] = (_Float16)v[1];
        Wt[64 + c4 + 2][k] = (_Float16)v[2];
        Wt[64 + c4 + 3][k] = (_Float16)v[3];
    }
    for (int i = tid; i < 12 * 128; i += 256) {          // zero pad ch 84..95
        int ch = 84 + (i >> 7);
        int k  = i & 127;
        Wt[ch][k] = (_Float16)0.f;
    }
    if (tid < NPAD) {
        float bv = 0.f;
        if (tid < 64)      bv = b_box[tid];
        else if (tid < 84) bv = b_cls[tid - 64];
        bias_s[tid] = bv;
    }
    __syncthreads();

    const int wave = tid >> 6;
    const int lane = tid & 63;
    const int c    = lane & 15;     // A channel-in-tile / B spatial-row / D col
    const int g    = lane >> 4;     // quarter-group; D row = 4g + reg

    const int mbase = blockIdx.x * 128 + wave * 32;      // 1600 blocks

    // ---- preload all x (16 dwordx4 in flight) ----
    f32x4v xv[4][2][2];
    const float* xbase = x + (size_t)(mbase + c) * Cc + g * 8;
    #pragma unroll
    for (int ks = 0; ks < 4; ++ks)
        #pragma unroll
        for (int rt = 0; rt < 2; ++rt) {
            const float* p = xbase + rt * 16 * Cc + ks * 32;
            xv[ks][rt][0] = *(const f32x4v*)p;
            xv[ks][rt][1] = *(const f32x4v*)(p + 4);
        }

    f32x4v acc[2][6];
    #pragma unroll
    for (int i = 0; i < 2; ++i)
        #pragma unroll
        for (int j = 0; j < 6; ++j)
            acc[i][j] = (f32x4v){0.f, 0.f, 0.f, 0.f};

    #pragma unroll
    for (int ks = 0; ks < 4; ++ks) {
        half8 wfrag[6];
        #pragma unroll
        for (int nt = 0; nt < 6; ++nt)
            wfrag[nt] = *(const half8*)&Wt[nt * 16 + c][ks * 32 + g * 8];

        #pragma unroll
        for (int rt = 0; rt < 2; ++rt) {
            f32x4v lo = xv[ks][rt][0], hi = xv[ks][rt][1];
            half8 b;
            b[0] = (_Float16)lo[0]; b[1] = (_Float16)lo[1];
            b[2] = (_Float16)lo[2]; b[3] = (_Float16)lo[3];
            b[4] = (_Float16)hi[0]; b[5] = (_Float16)hi[1];
            b[6] = (_Float16)hi[2]; b[7] = (_Float16)hi[3];
            #pragma unroll
            for (int nt = 0; nt < 6; ++nt)
                acc[rt][nt] = __builtin_amdgcn_mfma_f32_16x16x32_f16(wfrag[nt], b, acc[rt][nt], 0, 0, 0);
        }
    }

    const float sf = (float)stride_p[0];
    f32x4v bl[6];
    #pragma unroll
    for (int nt = 0; nt < 6; ++nt)
        bl[nt] = *(const f32x4v*)&bias_s[nt * 16 + g * 4];

    #pragma unroll
    for (int rt = 0; rt < 2; ++rt) {
        const int m   = mbase + rt * 16 + c;
        const int pos = m % HW;
        const int yp  = pos / Ww;
        const int xq  = pos - yp * Ww;
        const float ax = ((float)xq + 0.5f) * sf;
        const float ay = ((float)yp + 0.5f) * sf;

        // DFL softmax: channels t*16 + 4g + r; lane-local over r, 2 shfls over g.
        float dfl[4];
        #pragma unroll
        for (int t = 0; t < 4; ++t) {
            f32x4v v = acc[rt][t] + bl[t];
            float e0 = __expf(v[0]), e1 = __expf(v[1]);
            float e2 = __expf(v[2]), e3 = __expf(v[3]);
            float s  = e0 + e1 + e2 + e3;
            float ws = e1 + 2.f * e2 + 3.f * e3 + (float)(4 * g) * s;
            s  += __shfl_xor(s, 16, 64);
            s  += __shfl_xor(s, 32, 64);
            ws += __shfl_xor(ws, 16, 64);
            ws += __shfl_xor(ws, 32, 64);
            dfl[t] = ws / s;
        }
        const float w2 = dfl[2] - dfl[0], w3 = dfl[3] - dfl[1];

        float* op = out + (size_t)m * 24;

        // cls 0..15 live in tile 4 rows: ch 64+4g+r -> out[4+4g+r]
        f32x4v vA = acc[rt][4] + bl[4];
        f32x4v clsA;
        clsA[0] = sigm(vA[0]); clsA[1] = sigm(vA[1]);
        clsA[2] = sigm(vA[2]); clsA[3] = sigm(vA[3]);
        *(f32x4v*)(op + 4 + 4 * g) = clsA;

        if (g == 0) {
            f32x4v box = { ax + 0.5f * w2, ay + 0.5f * w3, w2, w3 };
            *(f32x4v*)op = box;
            // cls 16..19: tile 5 rows 0..3 (only g==0 holds them)
            f32x4v vB = acc[rt][5] + bl[5];
            f32x4v clsB;
            clsB[0] = sigm(vB[0]); clsB[1] = sigm(vB[1]);
            clsB[2] = sigm(vB[2]); clsB[3] = sigm(vB[3]);
            *(f32x4v*)(op + 20) = clsB;
        }
    }
}

extern "C" void kernel_launch(void* const* d_in, const int* in_sizes, int n_in,
                              void* d_out, int out_size, void* d_ws, size_t ws_size,
                              hipStream_t stream) {
    const float* x      = (const float*)d_in[0];
    const float* w_box  = (const float*)d_in[1];
    const float* b_box  = (const float*)d_in[2];
    const float* w_cls  = (const float*)d_in[3];
    const float* b_cls  = (const float*)d_in[4];
    const int*   stride_p = (const int*)d_in[5];
    float* out = (float*)d_out;

    dim3 grid(1600), block(256);
    hipLaunchKernelGGL(head_kernel, grid, block, 0, stream,
                       x, w_box, b_box, w_cls, b_cls, stride_p, out);
}